// Round 4
// baseline (496.937 us; speedup 1.0000x reference)
//
#include <hip/hip_runtime.h>
#include <hip/hip_bf16.h>
#include <cstdint>
#include <cstddef>

typedef __bf16 bf16;
typedef __attribute__((ext_vector_type(8))) __bf16 bf16x8;
typedef __attribute__((ext_vector_type(4))) __bf16 bf16x4v;
typedef __attribute__((ext_vector_type(4))) float f32x4;

#define TBL 3969
#define LOG2E 1.4426950408889634f
#define QK_SCALE 0.17677669529663687f

__device__ __forceinline__ f32x4 mfma16(bf16x8 a, bf16x8 b, f32x4 c) {
  return __builtin_amdgcn_mfma_f32_16x16x32_bf16(a, b, c, 0, 0, 0);
}
__device__ __forceinline__ float exp2_hw(float x) {
  float r; asm("v_exp_f32 %0, %1" : "=v"(r) : "v"(x)); return r;
}

// ---------------- prep: split x, transpose+split weights ----------------
__global__ __launch_bounds__(256) void prep_kernel(
    const float* __restrict__ x, const float* __restrict__ wqkv, const float* __restrict__ wproj,
    bf16* __restrict__ Xh, bf16* __restrict__ Xl,
    bf16* __restrict__ wqkvTh, bf16* __restrict__ wqkvTl,
    bf16* __restrict__ wprojTh, bf16* __restrict__ wprojTl)
{
  const int X4 = 16384 * 512 / 4;
  int e = blockIdx.x * 256 + threadIdx.x;
  if (e < X4) {
    f32x4 v = *(const f32x4*)(x + (size_t)e * 4);
    bf16x4v hi, lo;
    #pragma unroll
    for (int j = 0; j < 4; ++j) {
      bf16 h = (bf16)v[j];
      hi[j] = h;
      lo[j] = (bf16)(v[j] - (float)h);
    }
    *(bf16x4v*)(Xh + (size_t)e * 4) = hi;
    *(bf16x4v*)(Xl + (size_t)e * 4) = lo;
  } else if (e < X4 + 1536 * 512) {
    int e2 = e - X4;
    int n = e2 >> 9, k = e2 & 511;
    float v = wqkv[k * 1536 + n];
    bf16 h = (bf16)v;
    wqkvTh[e2] = h;
    wqkvTl[e2] = (bf16)(v - (float)h);
  } else {
    int e3 = e - (X4 + 1536 * 512);
    if (e3 < 512 * 512) {
      int n = e3 >> 9, k = e3 & 511;
      float v = wproj[k * 512 + n];
      bf16 h = (bf16)v;
      wprojTh[e3] = h;
      wprojTl[e3] = (bf16)(v - (float)h);
    }
  }
}

// ---------------- bias matrix: biasM[h][q][kv] = table[rel(q,kv)][h] * log2e (bf16) ----------------
__global__ __launch_bounds__(256) void bias_kernel(
    const float* __restrict__ btab, bf16* __restrict__ biasM)
{
  int e = blockIdx.x * 256 + threadIdx.x;       // 16*1024*128 threads, 8 kv each
  int h = e >> 17;
  int rest = e & 131071;
  int q = rest >> 7, kv0 = (rest & 127) * 8;
  int base_q = ((q >> 5) + 31) * 63 + (q & 31) + 31;
  bf16x8 pk;
  #pragma unroll
  for (int i = 0; i < 8; ++i) {
    int kv = kv0 + i;
    int idx = base_q - ((kv >> 5) * 63 + (kv & 31));
    pk[i] = (bf16)(btab[idx * 16 + h] * LOG2E);
  }
  *(bf16x8*)(biasM + (size_t)e * 8) = pk;
}

// ---------------- split-bf16 GEMM: C[M,N] = (Ah+Al) @ (Bh+Bl) + bias ----------------
// MODE 0: N=1536 -> Q(scaled,split), K per-head [bh][kv][32], V [bh][dsub][nd][n]
// MODE 1: N=512  -> fp32 out
template<int MODE>
__global__ __launch_bounds__(256) void gemm_kernel(
    const bf16* __restrict__ Ah, const bf16* __restrict__ Al,
    const bf16* __restrict__ BTh, const bf16* __restrict__ BTl,
    const float* __restrict__ bvec,
    bf16* __restrict__ Qh, bf16* __restrict__ Ql,
    bf16* __restrict__ Kp, bf16* __restrict__ Vt,
    float* __restrict__ out)
{
  constexpr int NT = (MODE == 0) ? 12 : 4;
  __shared__ bf16 Ash[128][40];
  __shared__ bf16 Asl[128][40];
  __shared__ bf16 Bsh[128][40];
  __shared__ bf16 Bsl[128][40];

  const int bx = blockIdx.x % NT;
  const int by = blockIdx.x / NT;
  const int row0 = by * 128, col0 = bx * 128;
  const int tid = threadIdx.x;
  const int lane = tid & 63, wave = tid >> 6;
  const int l15 = lane & 15, l4 = lane >> 4;
  const int wr = wave >> 1, wc = wave & 1;

  f32x4 acc[4][4];
  #pragma unroll
  for (int i = 0; i < 4; ++i)
    #pragma unroll
    for (int j = 0; j < 4; ++j) acc[i][j] = (f32x4){0.f, 0.f, 0.f, 0.f};

  for (int kt = 0; kt < 16; ++kt) {
    #pragma unroll
    for (int p = 0; p < 2; ++p) {
      int s = tid + p * 256;
      int r = s >> 2, c = (s & 3) * 8;
      size_t ao = (size_t)(row0 + r) * 512 + kt * 32 + c;
      size_t bo = (size_t)(col0 + r) * 512 + kt * 32 + c;
      *(bf16x8*)&Ash[r][c] = *(const bf16x8*)(Ah + ao);
      *(bf16x8*)&Asl[r][c] = *(const bf16x8*)(Al + ao);
      *(bf16x8*)&Bsh[r][c] = *(const bf16x8*)(BTh + bo);
      *(bf16x8*)&Bsl[r][c] = *(const bf16x8*)(BTl + bo);
    }
    __syncthreads();

    bf16x8 ah[4], al[4], bh[4], bl[4];
    #pragma unroll
    for (int mf = 0; mf < 4; ++mf) {
      int r = wr * 64 + mf * 16 + l15;
      ah[mf] = *(const bf16x8*)&Ash[r][l4 * 8];
      al[mf] = *(const bf16x8*)&Asl[r][l4 * 8];
    }
    #pragma unroll
    for (int nf = 0; nf < 4; ++nf) {
      int c = wc * 64 + nf * 16 + l15;
      bh[nf] = *(const bf16x8*)&Bsh[c][l4 * 8];
      bl[nf] = *(const bf16x8*)&Bsl[c][l4 * 8];
    }
    #pragma unroll
    for (int mf = 0; mf < 4; ++mf)
      #pragma unroll
      for (int nf = 0; nf < 4; ++nf) {
        f32x4 a = acc[mf][nf];
        a = mfma16(ah[mf], bh[nf], a);
        a = mfma16(ah[mf], bl[nf], a);
        a = mfma16(al[mf], bh[nf], a);
        acc[mf][nf] = a;
      }
    __syncthreads();
  }

  #pragma unroll
  for (int mf = 0; mf < 4; ++mf) {
    #pragma unroll
    for (int nf = 0; nf < 4; ++nf) {
      int colb = col0 + wc * 64 + nf * 16 + l15;
      float bb = bvec[colb];
      #pragma unroll
      for (int i = 0; i < 4; ++i) {
        int m = row0 + wr * 64 + mf * 16 + l4 * 4 + i;
        float v = acc[mf][nf][i] + bb;
        if (MODE == 1) {
          out[(size_t)m * 512 + colb] = v;
        } else {
          int t = colb >> 9, cc = colb & 511;
          int b = m >> 10, n = m & 1023;
          if (t == 0) {
            v *= (QK_SCALE * LOG2E);
            bf16 h = (bf16)v;
            Qh[(size_t)m * 512 + cc] = h;
            Ql[(size_t)m * 512 + cc] = (bf16)(v - (float)h);
          } else if (t == 1) {
            int hh = cc >> 5, d = cc & 31;
            Kp[((size_t)(b * 16 + hh) * 1024 + n) * 32 + d] = (bf16)v;
          } else {
            int hh = cc >> 5, d = cc & 31;
            size_t a = (((size_t)(b * 16 + hh) * 16 + (d & 15)) * 2 + (d >> 4)) * 1024 + n;
            Vt[a] = (bf16)v;
          }
        }
      }
    }
  }
}

// ---------------- fused flash attention: bias-matrix, exp2, ones-MFMA rowsum ----------------
// grid 4096: bid = qt*256 + (b*16+h) -> all q-tiles of one head land on one XCD (L2 reuse).
__global__ __launch_bounds__(256) void attn_kernel(
    const bf16* __restrict__ Qh, const bf16* __restrict__ Ql,
    const bf16* __restrict__ Kp, const bf16* __restrict__ Vt,
    const bf16* __restrict__ biasM,
    bf16* __restrict__ Oh, bf16* __restrict__ Ol)
{
  __shared__ bf16 Pt[4][16][72];
  const int bid = blockIdx.x;
  const int bh = bid & 255, qt = bid >> 8;
  const int h = bh & 15;
  const int tid = threadIdx.x, lane = tid & 63, wave = tid >> 6;
  const int l15 = lane & 15, l4 = lane >> 4;

  const int q0 = qt * 64 + wave * 16;
  const int m0 = (bh >> 4) * 1024 + q0;

  const size_t qoff = (size_t)(m0 + l15) * 512 + h * 32 + l4 * 8;
  const bf16x8 qfh = *(const bf16x8*)(Qh + qoff);
  const bf16x8 qfl = *(const bf16x8*)(Ql + qoff);

  // 32-bit running element offsets (uniform base + vgpr offset + imm)
  uint32_t koff = (uint32_t)bh * 32768u + (uint32_t)l15 * 32u + (uint32_t)l4 * 8u;
  uint32_t voff = ((uint32_t)bh * 16u + (uint32_t)l15) * 2048u + (uint32_t)l4 * 8u;
  uint32_t boff = ((uint32_t)h * 1024u + (uint32_t)(q0 + l15)) * 1024u + (uint32_t)l4 * 4u;

  bf16x8 ones;
  { union { uint32_t u[4]; bf16x8 v; } c;
    c.u[0] = c.u[1] = c.u[2] = c.u[3] = 0x3F803F80u; ones = c.v; }

  // prologue: K tile 0 + bias tile 0
  bf16x8 kfA[4], kfB[4];
  uint2 bwA[4], bwB[4];
  #pragma unroll
  for (int nf = 0; nf < 4; ++nf) {
    kfA[nf] = *(const bf16x8*)(Kp + koff + nf * 512);
    bwA[nf] = *(const uint2*)(biasM + boff + nf * 16);
  }
  boff += 64;

  f32x4 O0a = {0.f,0.f,0.f,0.f}, O0b = {0.f,0.f,0.f,0.f};
  f32x4 O1a = {0.f,0.f,0.f,0.f}, O1b = {0.f,0.f,0.f,0.f};
  f32x4 Ra  = {0.f,0.f,0.f,0.f}, Rb  = {0.f,0.f,0.f,0.f};

  auto tile = [&](bf16x8 (&kf)[4], bf16x8 (&kf2)[4], uint2 (&bw)[4], uint2 (&bw2)[4]) {
    // prefetch next K + next bias (consumed next call)
    koff += 2048;
    #pragma unroll
    for (int nf = 0; nf < 4; ++nf) {
      kf2[nf] = *(const bf16x8*)(Kp + koff + nf * 512);
      bw2[nf] = *(const uint2*)(biasM + boff + nf * 16);
    }
    boff += 64;
    // V for current tile (consumed ~300cy later at PV)
    bf16x8 vf[4];
    #pragma unroll
    for (int j = 0; j < 4; ++j) {
      int ks = j >> 1, nd = j & 1;
      vf[j] = *(const bf16x8*)(Vt + voff + nd * 1024 + ks * 32);
    }
    voff += 64;
    // per-nf: QK^T (swapped) -> +bias -> exp2 -> pack -> LDS
    #pragma unroll
    for (int nf = 0; nf < 4; ++nf) {
      f32x4 s = mfma16(kf[nf], qfh, (f32x4){0.f, 0.f, 0.f, 0.f});
      s = mfma16(kf[nf], qfl, s);
      uint32_t w0 = bw[nf].x, w1 = bw[nf].y;
      float b0 = __uint_as_float(w0 << 16);
      float b1 = __uint_as_float(w0 & 0xFFFF0000u);
      float b2 = __uint_as_float(w1 << 16);
      float b3 = __uint_as_float(w1 & 0xFFFF0000u);
      bf16x4v pk;
      pk[0] = (bf16)exp2_hw(s[0] + b0);
      pk[1] = (bf16)exp2_hw(s[1] + b1);
      pk[2] = (bf16)exp2_hw(s[2] + b2);
      pk[3] = (bf16)exp2_hw(s[3] + b3);
      *(bf16x4v*)&Pt[wave][l15][nf * 16 + l4 * 4] = pk;
    }
    // A-layout P fragments (same-wave LDS roundtrip, in-order DS)
    bf16x8 pf0 = *(const bf16x8*)&Pt[wave][l15][l4 * 8];
    bf16x8 pf1 = *(const bf16x8*)&Pt[wave][l15][32 + l4 * 8];
    // PV + rowsum via ones-MFMA (independent accumulator chains)
    O0a = mfma16(pf0, vf[0], O0a);
    O1a = mfma16(pf0, vf[1], O1a);
    Ra  = mfma16(pf0, ones, Ra);
    O0b = mfma16(pf1, vf[2], O0b);
    O1b = mfma16(pf1, vf[3], O1b);
    Rb  = mfma16(pf1, ones, Rb);
  };

  #pragma unroll 1
  for (int t = 0; t < 8; ++t) {
    tile(kfA, kfB, bwA, bwB);
    tile(kfB, kfA, bwB, bwA);
  }

  #pragma unroll
  for (int i = 0; i < 4; ++i) {
    float inv = 1.f / (Ra[i] + Rb[i]);
    float o0 = (O0a[i] + O0b[i]) * inv;
    float o1 = (O1a[i] + O1b[i]) * inv;
    size_t ro = (size_t)(m0 + l4 * 4 + i) * 512 + h * 32;
    bf16 h0 = (bf16)o0, h1 = (bf16)o1;
    Oh[ro + l15] = h0;       Ol[ro + l15] = (bf16)(o0 - (float)h0);
    Oh[ro + 16 + l15] = h1;  Ol[ro + 16 + l15] = (bf16)(o1 - (float)h1);
  }
}

// ---------------- launch ----------------
extern "C" void kernel_launch(void* const* d_in, const int* in_sizes, int n_in,
                              void* d_out, int out_size, void* d_ws, size_t ws_size,
                              hipStream_t stream) {
  const float* x     = (const float*)d_in[0];
  const float* wqkv  = (const float*)d_in[1];
  const float* bqkv  = (const float*)d_in[2];
  const float* wproj = (const float*)d_in[3];
  const float* bproj = (const float*)d_in[4];
  const float* btab  = (const float*)d_in[5];
  // d_in[6] rel_index: unused (index computed analytically)
  float* out = (float*)d_out;

  char* ws = (char*)d_ws;
  size_t off = 0;
  auto walloc = [&](size_t bytes) {
    void* p = ws + off;
    off += (bytes + 255) & ~(size_t)255;
    return p;
  };
  bf16* Xh      = (bf16*)walloc((size_t)16384 * 512 * 2);
  bf16* Xl      = (bf16*)walloc((size_t)16384 * 512 * 2);
  bf16* wqkvTh  = (bf16*)walloc((size_t)1536 * 512 * 2);
  bf16* wqkvTl  = (bf16*)walloc((size_t)1536 * 512 * 2);
  bf16* wprojTh = (bf16*)walloc((size_t)512 * 512 * 2);
  bf16* wprojTl = (bf16*)walloc((size_t)512 * 512 * 2);
  bf16* Qh      = (bf16*)walloc((size_t)16384 * 512 * 2);
  bf16* Ql      = (bf16*)walloc((size_t)16384 * 512 * 2);
  bf16* Kp      = (bf16*)walloc((size_t)16384 * 512 * 2 + 65536);  // +pad (last prefetch)
  bf16* Vt      = (bf16*)walloc((size_t)16384 * 512 * 2);
  bf16* biasM   = (bf16*)walloc((size_t)16 * 1024 * 1024 * 2 + 65536);  // +pad
  bf16* Oh      = (bf16*)walloc((size_t)16384 * 512 * 2);
  bf16* Ol      = (bf16*)walloc((size_t)16384 * 512 * 2);

  const int prep_total = 16384 * 512 / 4 + 1536 * 512 + 512 * 512;
  prep_kernel<<<(prep_total + 255) / 256, 256, 0, stream>>>(
      x, wqkv, wproj, Xh, Xl, wqkvTh, wqkvTl, wprojTh, wprojTl);

  bias_kernel<<<16 * 1024 * 128 / 256, 256, 0, stream>>>(btab, biasM);

  gemm_kernel<0><<<12 * 128, 256, 0, stream>>>(
      Xh, Xl, wqkvTh, wqkvTl, bqkv, Qh, Ql, Kp, Vt, nullptr);

  attn_kernel<<<4096, 256, 0, stream>>>(Qh, Ql, Kp, Vt, biasM, Oh, Ol);

  gemm_kernel<1><<<4 * 128, 256, 0, stream>>>(
      Oh, Ol, wprojTh, wprojTl, bproj,
      nullptr, nullptr, nullptr, nullptr, out);
}

// Round 5
// 420.825 us; speedup vs baseline: 1.1809x; 1.1809x over previous
//
#include <hip/hip_runtime.h>
#include <hip/hip_bf16.h>
#include <cstdint>
#include <cstddef>

typedef __bf16 bf16;
typedef __attribute__((ext_vector_type(8))) __bf16 bf16x8;
typedef __attribute__((ext_vector_type(4))) __bf16 bf16x4v;
typedef __attribute__((ext_vector_type(4))) float f32x4;
typedef __attribute__((ext_vector_type(16))) float f32x16;

#define TBL 3969
#define LOG2E 1.4426950408889634f
#define QK_SCALE 0.17677669529663687f

__device__ __forceinline__ f32x4 mfma16(bf16x8 a, bf16x8 b, f32x4 c) {
  return __builtin_amdgcn_mfma_f32_16x16x32_bf16(a, b, c, 0, 0, 0);
}
__device__ __forceinline__ f32x16 mfma32(bf16x8 a, bf16x8 b, f32x16 c) {
  return __builtin_amdgcn_mfma_f32_32x32x16_bf16(a, b, c, 0, 0, 0);
}
__device__ __forceinline__ float exp2_hw(float x) {
  float r; asm("v_exp_f32 %0, %1" : "=v"(r) : "v"(x)); return r;
}
__device__ __forceinline__ uint32_t cvtpk_bf16(float a, float b) {
  uint32_t r; asm("v_cvt_pk_bf16_f32 %0, %1, %2" : "=v"(r) : "v"(a), "v"(b)); return r;
}
__device__ __forceinline__ void pl32swap(uint32_t& a, uint32_t& b) {
  asm("v_permlane32_swap_b32 %0, %1" : "+v"(a), "+v"(b));
}

// ---------------- prep: split x, transpose+split weights ----------------
__global__ __launch_bounds__(256) void prep_kernel(
    const float* __restrict__ x, const float* __restrict__ wqkv, const float* __restrict__ wproj,
    bf16* __restrict__ Xh, bf16* __restrict__ Xl,
    bf16* __restrict__ wqkvTh, bf16* __restrict__ wqkvTl,
    bf16* __restrict__ wprojTh, bf16* __restrict__ wprojTl)
{
  const int X4 = 16384 * 512 / 4;
  int e = blockIdx.x * 256 + threadIdx.x;
  if (e < X4) {
    f32x4 v = *(const f32x4*)(x + (size_t)e * 4);
    bf16x4v hi, lo;
    #pragma unroll
    for (int j = 0; j < 4; ++j) {
      bf16 h = (bf16)v[j];
      hi[j] = h;
      lo[j] = (bf16)(v[j] - (float)h);
    }
    *(bf16x4v*)(Xh + (size_t)e * 4) = hi;
    *(bf16x4v*)(Xl + (size_t)e * 4) = lo;
  } else if (e < X4 + 1536 * 512) {
    int e2 = e - X4;
    int n = e2 >> 9, k = e2 & 511;
    float v = wqkv[k * 1536 + n];
    bf16 h = (bf16)v;
    wqkvTh[e2] = h;
    wqkvTl[e2] = (bf16)(v - (float)h);
  } else {
    int e3 = e - (X4 + 1536 * 512);
    if (e3 < 512 * 512) {
      int n = e3 >> 9, k = e3 & 511;
      float v = wproj[k * 512 + n];
      bf16 h = (bf16)v;
      wprojTh[e3] = h;
      wprojTl[e3] = (bf16)(v - (float)h);
    }
  }
}

// ---------------- bias matrix: biasM[h][q][kv] = table[rel(q,kv)][h] * log2e (bf16) ----------------
__global__ __launch_bounds__(256) void bias_kernel(
    const float* __restrict__ btab, bf16* __restrict__ biasM)
{
  int e = blockIdx.x * 256 + threadIdx.x;
  int h = e >> 17;
  int rest = e & 131071;
  int q = rest >> 7, kv0 = (rest & 127) * 8;
  int base_q = ((q >> 5) + 31) * 63 + (q & 31) + 31;
  bf16x8 pk;
  #pragma unroll
  for (int i = 0; i < 8; ++i) {
    int kv = kv0 + i;
    int idx = base_q - ((kv >> 5) * 63 + (kv & 31));
    pk[i] = (bf16)(btab[idx * 16 + h] * LOG2E);
  }
  *(bf16x8*)(biasM + (size_t)e * 8) = pk;
}

// ---------------- split-bf16 GEMM: C[M,N] = (Ah+Al) @ (Bh+Bl) + bias ----------------
// MODE 0: N=1536 -> Q(scaled,split), K [bh][kv][32], V [bh][d][n]
// MODE 1: N=512  -> fp32 out
template<int MODE>
__global__ __launch_bounds__(256) void gemm_kernel(
    const bf16* __restrict__ Ah, const bf16* __restrict__ Al,
    const bf16* __restrict__ BTh, const bf16* __restrict__ BTl,
    const float* __restrict__ bvec,
    bf16* __restrict__ Qh, bf16* __restrict__ Ql,
    bf16* __restrict__ Kp, bf16* __restrict__ Vt,
    float* __restrict__ out)
{
  constexpr int NT = (MODE == 0) ? 12 : 4;
  __shared__ bf16 Ash[128][40];
  __shared__ bf16 Asl[128][40];
  __shared__ bf16 Bsh[128][40];
  __shared__ bf16 Bsl[128][40];

  const int bx = blockIdx.x % NT;
  const int by = blockIdx.x / NT;
  const int row0 = by * 128, col0 = bx * 128;
  const int tid = threadIdx.x;
  const int lane = tid & 63, wave = tid >> 6;
  const int l15 = lane & 15, l4 = lane >> 4;
  const int wr = wave >> 1, wc = wave & 1;

  f32x4 acc[4][4];
  #pragma unroll
  for (int i = 0; i < 4; ++i)
    #pragma unroll
    for (int j = 0; j < 4; ++j) acc[i][j] = (f32x4){0.f, 0.f, 0.f, 0.f};

  for (int kt = 0; kt < 16; ++kt) {
    #pragma unroll
    for (int p = 0; p < 2; ++p) {
      int s = tid + p * 256;
      int r = s >> 2, c = (s & 3) * 8;
      size_t ao = (size_t)(row0 + r) * 512 + kt * 32 + c;
      size_t bo = (size_t)(col0 + r) * 512 + kt * 32 + c;
      *(bf16x8*)&Ash[r][c] = *(const bf16x8*)(Ah + ao);
      *(bf16x8*)&Asl[r][c] = *(const bf16x8*)(Al + ao);
      *(bf16x8*)&Bsh[r][c] = *(const bf16x8*)(BTh + bo);
      *(bf16x8*)&Bsl[r][c] = *(const bf16x8*)(BTl + bo);
    }
    __syncthreads();

    bf16x8 ah[4], al[4], bh[4], bl[4];
    #pragma unroll
    for (int mf = 0; mf < 4; ++mf) {
      int r = wr * 64 + mf * 16 + l15;
      ah[mf] = *(const bf16x8*)&Ash[r][l4 * 8];
      al[mf] = *(const bf16x8*)&Asl[r][l4 * 8];
    }
    #pragma unroll
    for (int nf = 0; nf < 4; ++nf) {
      int c = wc * 64 + nf * 16 + l15;
      bh[nf] = *(const bf16x8*)&Bsh[c][l4 * 8];
      bl[nf] = *(const bf16x8*)&Bsl[c][l4 * 8];
    }
    #pragma unroll
    for (int mf = 0; mf < 4; ++mf)
      #pragma unroll
      for (int nf = 0; nf < 4; ++nf) {
        f32x4 a = acc[mf][nf];
        a = mfma16(ah[mf], bh[nf], a);
        a = mfma16(ah[mf], bl[nf], a);
        a = mfma16(al[mf], bh[nf], a);
        acc[mf][nf] = a;
      }
    __syncthreads();
  }

  #pragma unroll
  for (int mf = 0; mf < 4; ++mf) {
    #pragma unroll
    for (int nf = 0; nf < 4; ++nf) {
      int colb = col0 + wc * 64 + nf * 16 + l15;
      float bb = bvec[colb];
      #pragma unroll
      for (int i = 0; i < 4; ++i) {
        int m = row0 + wr * 64 + mf * 16 + l4 * 4 + i;
        float v = acc[mf][nf][i] + bb;
        if (MODE == 1) {
          out[(size_t)m * 512 + colb] = v;
        } else {
          int t = colb >> 9, cc = colb & 511;
          int b = m >> 10, n = m & 1023;
          if (t == 0) {
            v *= (QK_SCALE * LOG2E);
            bf16 h = (bf16)v;
            Qh[(size_t)m * 512 + cc] = h;
            Ql[(size_t)m * 512 + cc] = (bf16)(v - (float)h);
          } else if (t == 1) {
            int hh = cc >> 5, d = cc & 31;
            Kp[((size_t)(b * 16 + hh) * 1024 + n) * 32 + d] = (bf16)v;
          } else {
            int hh = cc >> 5, d = cc & 31;
            Vt[((size_t)(b * 16 + hh) * 32 + d) * 1024 + n] = (bf16)v;
          }
        }
      }
    }
  }
}

// ---------------- fused flash attention: 32x32 MFMA, permlane P-exchange, no LDS ----------------
// grid 2048: bid = qt*256 + bh. Block = 4 independent waves, each owns 32 q rows.
__global__ __launch_bounds__(256) void attn_kernel(
    const bf16* __restrict__ Qh, const bf16* __restrict__ Ql,
    const bf16* __restrict__ Kp, const bf16* __restrict__ Vt,
    const bf16* __restrict__ biasM,
    bf16* __restrict__ Oh, bf16* __restrict__ Ol)
{
  const int bid = blockIdx.x;
  const int bh = bid & 255, qt = bid >> 8;    // qt 0..7
  const int h = bh & 15;
  const int tid = threadIdx.x, lane = tid & 63, wave = tid >> 6;
  const int lq = lane & 31, hi5 = lane >> 5;

  const int qloc = qt * 128 + wave * 32;          // q within this (b,h)
  const int m0w  = (bh >> 4) * 1024 + qloc;       // global row base

  // Q B-fragments (col=q=lq, k=d=8*hi5+j), two d-halves, hi+lo split
  const uint32_t qoff = (uint32_t)(m0w + lq) * 512u + (uint32_t)h * 32u + (uint32_t)hi5 * 8u;
  const bf16x8 qh0 = *(const bf16x8*)(Qh + qoff);
  const bf16x8 qh1 = *(const bf16x8*)(Qh + qoff + 16);
  const bf16x8 ql0 = *(const bf16x8*)(Ql + qoff);
  const bf16x8 ql1 = *(const bf16x8*)(Ql + qoff + 16);

  // running 32-bit element offsets
  uint32_t koff = (uint32_t)bh * 32768u + (uint32_t)lq * 32u + (uint32_t)hi5 * 8u;   // [bh][kv][32]
  uint32_t voff = (uint32_t)bh * 32768u + (uint32_t)lq * 1024u + (uint32_t)hi5 * 8u; // [bh][d][1024]
  uint32_t boff = ((uint32_t)h * 1024u + (uint32_t)(qloc + lq)) * 1024u + (uint32_t)hi5 * 4u;

  // prologue: tiles 0 (A bufs) and 1 (B bufs)
  bf16x8 kA0 = *(const bf16x8*)(Kp + koff);
  bf16x8 kA1 = *(const bf16x8*)(Kp + koff + 16);
  bf16x8 kB0 = *(const bf16x8*)(Kp + koff + 1024);
  bf16x8 kB1 = *(const bf16x8*)(Kp + koff + 1040);
  bf16x8 vA0 = *(const bf16x8*)(Vt + voff);
  bf16x8 vA1 = *(const bf16x8*)(Vt + voff + 16);
  bf16x8 vB0 = *(const bf16x8*)(Vt + voff + 32);
  bf16x8 vB1 = *(const bf16x8*)(Vt + voff + 48);
  uint2 bA0 = *(const uint2*)(biasM + boff);
  uint2 bA1 = *(const uint2*)(biasM + boff + 8);
  uint2 bA2 = *(const uint2*)(biasM + boff + 16);
  uint2 bA3 = *(const uint2*)(biasM + boff + 24);
  uint2 bB0 = *(const uint2*)(biasM + boff + 32);
  uint2 bB1 = *(const uint2*)(biasM + boff + 40);
  uint2 bB2 = *(const uint2*)(biasM + boff + 48);
  uint2 bB3 = *(const uint2*)(biasM + boff + 56);

  f32x16 O;
  #pragma unroll
  for (int i = 0; i < 16; ++i) O[i] = 0.f;
  f32x4 racc = {0.f, 0.f, 0.f, 0.f};

  union U8 { uint32_t u[4]; bf16x8 v; };

  auto tile = [&](bf16x8& K0, bf16x8& K1, bf16x8& V0, bf16x8& V1,
                  uint2& B0, uint2& B1, uint2& B2, uint2& B3,
                  uint32_t kpre, uint32_t vpre, uint32_t bpre) {
    // S^T[kv][q] = K · (Qh + Ql)
    f32x16 S;
    #pragma unroll
    for (int i = 0; i < 16; ++i) S[i] = 0.f;
    S = mfma32(K0, qh0, S);
    S = mfma32(K1, qh1, S);
    S = mfma32(K0, ql0, S);
    S = mfma32(K1, ql1, S);
    // refill K (tile t+2); pin issue point
    K0 = *(const bf16x8*)(Kp + koff + kpre);
    K1 = *(const bf16x8*)(Kp + koff + kpre + 16);
    __builtin_amdgcn_sched_barrier(0);
    // bias + exp2 (reg r -> kv = (r&3) + 8*(r>>2) + 4*hi5)
    float e[16];
#define BGRP(g, W)                                          \
    { float b0 = __uint_as_float((W).x << 16);              \
      float b1 = __uint_as_float((W).x & 0xFFFF0000u);      \
      float b2 = __uint_as_float((W).y << 16);              \
      float b3 = __uint_as_float((W).y & 0xFFFF0000u);      \
      e[4*(g)+0] = exp2_hw(S[4*(g)+0] + b0);                \
      e[4*(g)+1] = exp2_hw(S[4*(g)+1] + b1);                \
      e[4*(g)+2] = exp2_hw(S[4*(g)+2] + b2);                \
      e[4*(g)+3] = exp2_hw(S[4*(g)+3] + b3);                \
      racc[0] += e[4*(g)+0]; racc[1] += e[4*(g)+1];         \
      racc[2] += e[4*(g)+2]; racc[3] += e[4*(g)+3]; }
    BGRP(0, B0) BGRP(1, B1) BGRP(2, B2) BGRP(3, B3)
#undef BGRP
    // refill bias (tile t+2)
    B0 = *(const uint2*)(biasM + boff + bpre);
    B1 = *(const uint2*)(biasM + boff + bpre + 8);
    B2 = *(const uint2*)(biasM + boff + bpre + 16);
    B3 = *(const uint2*)(biasM + boff + bpre + 24);
    __builtin_amdgcn_sched_barrier(0);
    // pack P -> bf16 pairs, lane-half exchange -> A-fragments
    uint32_t u0 = cvtpk_bf16(e[0],  e[1]);
    uint32_t u1 = cvtpk_bf16(e[2],  e[3]);
    uint32_t u2 = cvtpk_bf16(e[4],  e[5]);
    uint32_t u3 = cvtpk_bf16(e[6],  e[7]);
    uint32_t u4 = cvtpk_bf16(e[8],  e[9]);
    uint32_t u5 = cvtpk_bf16(e[10], e[11]);
    uint32_t u6 = cvtpk_bf16(e[12], e[13]);
    uint32_t u7 = cvtpk_bf16(e[14], e[15]);
    pl32swap(u0, u2);
    pl32swap(u1, u3);
    pl32swap(u4, u6);
    pl32swap(u5, u7);
    U8 a1; a1.u[0] = u0; a1.u[1] = u1; a1.u[2] = u2; a1.u[3] = u3;
    U8 a2; a2.u[0] = u4; a2.u[1] = u5; a2.u[2] = u6; a2.u[3] = u7;
    // O[q][dout] += P @ V
    O = mfma32(a1.v, V0, O);
    O = mfma32(a2.v, V1, O);
    // refill V (tile t+2)
    V0 = *(const bf16x8*)(Vt + voff + vpre);
    V1 = *(const bf16x8*)(Vt + voff + vpre + 16);
    __builtin_amdgcn_sched_barrier(0);
  };

  #pragma unroll 1
  for (int it = 0; it < 16; ++it) {
    tile(kA0, kA1, vA0, vA1, bA0, bA1, bA2, bA3, 2048u, 64u, 64u);
    tile(kB0, kB1, vB0, vB1, bB0, bB1, bB2, bB3, 3072u, 96u, 96u);
    koff += 2048u; voff += 64u; boff += 64u;
  }

  // row sums: lane holds sum over its kv-slots for q=lq; partner lane has the rest
  float rsum = (racc[0] + racc[1]) + (racc[2] + racc[3]);
  rsum += __shfl_xor(rsum, 32);

  #pragma unroll
  for (int r = 0; r < 16; ++r) {
    int qrow = (r & 3) + 8 * (r >> 2) + 4 * hi5;
    float tot = __shfl(rsum, qrow);      // lanes 0..31 hold q totals
    float o = O[r] / tot;
    size_t ro = (size_t)(m0w + qrow) * 512 + h * 32 + lq;
    bf16 h0 = (bf16)o;
    Oh[ro] = h0;
    Ol[ro] = (bf16)(o - (float)h0);
  }
}

// ---------------- launch ----------------
extern "C" void kernel_launch(void* const* d_in, const int* in_sizes, int n_in,
                              void* d_out, int out_size, void* d_ws, size_t ws_size,
                              hipStream_t stream) {
  const float* x     = (const float*)d_in[0];
  const float* wqkv  = (const float*)d_in[1];
  const float* bqkv  = (const float*)d_in[2];
  const float* wproj = (const float*)d_in[3];
  const float* bproj = (const float*)d_in[4];
  const float* btab  = (const float*)d_in[5];
  // d_in[6] rel_index: unused (index computed analytically)
  float* out = (float*)d_out;

  char* ws = (char*)d_ws;
  size_t off = 0;
  auto walloc = [&](size_t bytes) {
    void* p = ws + off;
    off += (bytes + 255) & ~(size_t)255;
    return p;
  };
  bf16* Xh      = (bf16*)walloc((size_t)16384 * 512 * 2);
  bf16* Xl      = (bf16*)walloc((size_t)16384 * 512 * 2);
  bf16* wqkvTh  = (bf16*)walloc((size_t)1536 * 512 * 2);
  bf16* wqkvTl  = (bf16*)walloc((size_t)1536 * 512 * 2);
  bf16* wprojTh = (bf16*)walloc((size_t)512 * 512 * 2);
  bf16* wprojTl = (bf16*)walloc((size_t)512 * 512 * 2);
  bf16* Qh      = (bf16*)walloc((size_t)16384 * 512 * 2);
  bf16* Ql      = (bf16*)walloc((size_t)16384 * 512 * 2);
  bf16* Kp      = (bf16*)walloc((size_t)16384 * 512 * 2 + 65536);
  bf16* Vt      = (bf16*)walloc((size_t)16384 * 512 * 2 + 65536);
  bf16* biasM   = (bf16*)walloc((size_t)16 * 1024 * 1024 * 2 + 65536);
  bf16* Oh      = (bf16*)walloc((size_t)16384 * 512 * 2);
  bf16* Ol      = (bf16*)walloc((size_t)16384 * 512 * 2);

  const int prep_total = 16384 * 512 / 4 + 1536 * 512 + 512 * 512;
  prep_kernel<<<(prep_total + 255) / 256, 256, 0, stream>>>(
      x, wqkv, wproj, Xh, Xl, wqkvTh, wqkvTl, wprojTh, wprojTl);

  bias_kernel<<<16 * 1024 * 128 / 256, 256, 0, stream>>>(btab, biasM);

  gemm_kernel<0><<<12 * 128, 256, 0, stream>>>(
      Xh, Xl, wqkvTh, wqkvTl, bqkv, Qh, Ql, Kp, Vt, nullptr);

  attn_kernel<<<2048, 256, 0, stream>>>(Qh, Ql, Kp, Vt, biasM, Oh, Ol);

  gemm_kernel<1><<<4 * 128, 256, 0, stream>>>(
      Oh, Ol, wprojTh, wprojTl, bproj,
      nullptr, nullptr, nullptr, nullptr, out);
}

// Round 6
// 419.533 us; speedup vs baseline: 1.1845x; 1.0031x over previous
//
#include <hip/hip_runtime.h>
#include <hip/hip_bf16.h>
#include <cstdint>
#include <cstddef>

typedef __bf16 bf16;
typedef __attribute__((ext_vector_type(8))) __bf16 bf16x8;
typedef __attribute__((ext_vector_type(4))) __bf16 bf16x4v;
typedef __attribute__((ext_vector_type(4))) float f32x4;
typedef __attribute__((ext_vector_type(16))) float f32x16;

#define TBL 3969
#define LOG2E 1.4426950408889634f
#define QK_SCALE 0.17677669529663687f

__device__ __forceinline__ f32x4 mfma16(bf16x8 a, bf16x8 b, f32x4 c) {
  return __builtin_amdgcn_mfma_f32_16x16x32_bf16(a, b, c, 0, 0, 0);
}
__device__ __forceinline__ f32x16 mfma32(bf16x8 a, bf16x8 b, f32x16 c) {
  return __builtin_amdgcn_mfma_f32_32x32x16_bf16(a, b, c, 0, 0, 0);
}
__device__ __forceinline__ float exp2_hw(float x) {
  float r; asm("v_exp_f32 %0, %1" : "=v"(r) : "v"(x)); return r;
}
__device__ __forceinline__ uint32_t cvtpk_bf16(float a, float b) {
  uint32_t r; asm("v_cvt_pk_bf16_f32 %0, %1, %2" : "=v"(r) : "v"(a), "v"(b)); return r;
}
__device__ __forceinline__ void pl32swap(uint32_t& a, uint32_t& b) {
  asm("v_permlane32_swap_b32 %0, %1" : "+v"(a), "+v"(b));
}

// ---------------- prep: split x, transpose+split weights ----------------
__global__ __launch_bounds__(256) void prep_kernel(
    const float* __restrict__ x, const float* __restrict__ wqkv, const float* __restrict__ wproj,
    bf16* __restrict__ Xh, bf16* __restrict__ Xl,
    bf16* __restrict__ wqkvTh, bf16* __restrict__ wqkvTl,
    bf16* __restrict__ wprojTh, bf16* __restrict__ wprojTl)
{
  const int X4 = 16384 * 512 / 4;
  int e = blockIdx.x * 256 + threadIdx.x;
  if (e < X4) {
    f32x4 v = *(const f32x4*)(x + (size_t)e * 4);
    bf16x4v hi, lo;
    #pragma unroll
    for (int j = 0; j < 4; ++j) {
      bf16 h = (bf16)v[j];
      hi[j] = h;
      lo[j] = (bf16)(v[j] - (float)h);
    }
    *(bf16x4v*)(Xh + (size_t)e * 4) = hi;
    *(bf16x4v*)(Xl + (size_t)e * 4) = lo;
  } else if (e < X4 + 1536 * 512) {
    int e2 = e - X4;
    int n = e2 >> 9, k = e2 & 511;
    float v = wqkv[k * 1536 + n];
    bf16 h = (bf16)v;
    wqkvTh[e2] = h;
    wqkvTl[e2] = (bf16)(v - (float)h);
  } else {
    int e3 = e - (X4 + 1536 * 512);
    if (e3 < 512 * 512) {
      int n = e3 >> 9, k = e3 & 511;
      float v = wproj[k * 512 + n];
      bf16 h = (bf16)v;
      wprojTh[e3] = h;
      wprojTl[e3] = (bf16)(v - (float)h);
    }
  }
}

// ---------------- bias matrix: biasM[h][q][kv] = table[rel(q,kv)][h] * log2e (bf16) ----------------
__global__ __launch_bounds__(256) void bias_kernel(
    const float* __restrict__ btab, bf16* __restrict__ biasM)
{
  int e = blockIdx.x * 256 + threadIdx.x;
  int h = e >> 17;
  int rest = e & 131071;
  int q = rest >> 7, kv0 = (rest & 127) * 8;
  int base_q = ((q >> 5) + 31) * 63 + (q & 31) + 31;
  bf16x8 pk;
  #pragma unroll
  for (int i = 0; i < 8; ++i) {
    int kv = kv0 + i;
    int idx = base_q - ((kv >> 5) * 63 + (kv & 31));
    pk[i] = (bf16)(btab[idx * 16 + h] * LOG2E);
  }
  *(bf16x8*)(biasM + (size_t)e * 8) = pk;
}

// ---------------- split-bf16 GEMM: C[M,N] = (Ah+Al) @ (Bh+Bl) + bias ----------------
// MODE 0: N=1536 -> Q(scaled,split), K [bh][kv][32], V [bh][d][n]
// MODE 1: N=512  -> fp32 out
template<int MODE>
__global__ __launch_bounds__(256) void gemm_kernel(
    const bf16* __restrict__ Ah, const bf16* __restrict__ Al,
    const bf16* __restrict__ BTh, const bf16* __restrict__ BTl,
    const float* __restrict__ bvec,
    bf16* __restrict__ Qh, bf16* __restrict__ Ql,
    bf16* __restrict__ Kp, bf16* __restrict__ Vt,
    float* __restrict__ out)
{
  constexpr int NT = (MODE == 0) ? 12 : 4;
  __shared__ bf16 Ash[128][40];
  __shared__ bf16 Asl[128][40];
  __shared__ bf16 Bsh[128][40];
  __shared__ bf16 Bsl[128][40];

  const int bx = blockIdx.x % NT;
  const int by = blockIdx.x / NT;
  const int row0 = by * 128, col0 = bx * 128;
  const int tid = threadIdx.x;
  const int lane = tid & 63, wave = tid >> 6;
  const int l15 = lane & 15, l4 = lane >> 4;
  const int wr = wave >> 1, wc = wave & 1;

  f32x4 acc[4][4];
  #pragma unroll
  for (int i = 0; i < 4; ++i)
    #pragma unroll
    for (int j = 0; j < 4; ++j) acc[i][j] = (f32x4){0.f, 0.f, 0.f, 0.f};

  for (int kt = 0; kt < 16; ++kt) {
    #pragma unroll
    for (int p = 0; p < 2; ++p) {
      int s = tid + p * 256;
      int r = s >> 2, c = (s & 3) * 8;
      size_t ao = (size_t)(row0 + r) * 512 + kt * 32 + c;
      size_t bo = (size_t)(col0 + r) * 512 + kt * 32 + c;
      *(bf16x8*)&Ash[r][c] = *(const bf16x8*)(Ah + ao);
      *(bf16x8*)&Asl[r][c] = *(const bf16x8*)(Al + ao);
      *(bf16x8*)&Bsh[r][c] = *(const bf16x8*)(BTh + bo);
      *(bf16x8*)&Bsl[r][c] = *(const bf16x8*)(BTl + bo);
    }
    __syncthreads();

    bf16x8 ah[4], al[4], bh[4], bl[4];
    #pragma unroll
    for (int mf = 0; mf < 4; ++mf) {
      int r = wr * 64 + mf * 16 + l15;
      ah[mf] = *(const bf16x8*)&Ash[r][l4 * 8];
      al[mf] = *(const bf16x8*)&Asl[r][l4 * 8];
    }
    #pragma unroll
    for (int nf = 0; nf < 4; ++nf) {
      int c = wc * 64 + nf * 16 + l15;
      bh[nf] = *(const bf16x8*)&Bsh[c][l4 * 8];
      bl[nf] = *(const bf16x8*)&Bsl[c][l4 * 8];
    }
    #pragma unroll
    for (int mf = 0; mf < 4; ++mf)
      #pragma unroll
      for (int nf = 0; nf < 4; ++nf) {
        f32x4 a = acc[mf][nf];
        a = mfma16(ah[mf], bh[nf], a);
        a = mfma16(ah[mf], bl[nf], a);
        a = mfma16(al[mf], bh[nf], a);
        acc[mf][nf] = a;
      }
    __syncthreads();
  }

  #pragma unroll
  for (int mf = 0; mf < 4; ++mf) {
    #pragma unroll
    for (int nf = 0; nf < 4; ++nf) {
      int colb = col0 + wc * 64 + nf * 16 + l15;
      float bb = bvec[colb];
      #pragma unroll
      for (int i = 0; i < 4; ++i) {
        int m = row0 + wr * 64 + mf * 16 + l4 * 4 + i;
        float v = acc[mf][nf][i] + bb;
        if (MODE == 1) {
          out[(size_t)m * 512 + colb] = v;
        } else {
          int t = colb >> 9, cc = colb & 511;
          int b = m >> 10, n = m & 1023;
          if (t == 0) {
            v *= (QK_SCALE * LOG2E);
            bf16 h = (bf16)v;
            Qh[(size_t)m * 512 + cc] = h;
            Ql[(size_t)m * 512 + cc] = (bf16)(v - (float)h);
          } else if (t == 1) {
            int hh = cc >> 5, d = cc & 31;
            Kp[((size_t)(b * 16 + hh) * 1024 + n) * 32 + d] = (bf16)v;
          } else {
            int hh = cc >> 5, d = cc & 31;
            Vt[((size_t)(b * 16 + hh) * 32 + d) * 1024 + n] = (bf16)v;
          }
        }
      }
    }
  }
}

// ---------------- fused flash attention: 32x32 MFMA, bias C-init, counted-vmcnt pipeline ----------------
// grid 2048. Swizzle: xcd = bid&7 owns heads {2*xcd, 2*xcd+1}; within an h, the
// 16 batch-blocks of one qt run adjacent -> bias slice (512KB) L2-reused 16x.
__global__ __launch_bounds__(256) void attn_kernel(
    const bf16* __restrict__ Qh, const bf16* __restrict__ Ql,
    const bf16* __restrict__ Kp, const bf16* __restrict__ Vt,
    const bf16* __restrict__ biasM,
    bf16* __restrict__ Oh, bf16* __restrict__ Ol)
{
  const int bid = blockIdx.x;
  const int xcd = bid & 7, slot = bid >> 3;          // slot 0..255
  const int h = xcd * 2 + (slot >> 7);               // 2 heads per XCD
  const int rest = slot & 127;
  const int qt = rest >> 4, b = rest & 15;           // 8 qt x 16 b
  const int bh = b * 16 + h;
  const int tid = threadIdx.x, lane = tid & 63, wave = tid >> 6;
  const int lq = lane & 31, hi5 = lane >> 5;

  const int qloc = qt * 128 + wave * 32;
  const int m0w  = b * 1024 + qloc;

  // Q B-fragments (col=q=lq, k=d=8*hi5+j), two d-halves, hi+lo split
  const uint32_t qoff = (uint32_t)(m0w + lq) * 512u + (uint32_t)h * 32u + (uint32_t)hi5 * 8u;
  const bf16x8 qh0 = *(const bf16x8*)(Qh + qoff);
  const bf16x8 qh1 = *(const bf16x8*)(Qh + qoff + 16);
  const bf16x8 ql0 = *(const bf16x8*)(Ql + qoff);
  const bf16x8 ql1 = *(const bf16x8*)(Ql + qoff + 16);

  // running 32-bit element offsets
  uint32_t koff = (uint32_t)bh * 32768u + (uint32_t)lq * 32u + (uint32_t)hi5 * 8u;   // [bh][kv][32]
  uint32_t voff = (uint32_t)bh * 32768u + (uint32_t)lq * 1024u + (uint32_t)hi5 * 8u; // [bh][d][1024]
  uint32_t boff = ((uint32_t)h * 1024u + (uint32_t)(qloc + lq)) * 1024u + (uint32_t)hi5 * 4u;

  // prologue: issue tiles 0 (A) and 1 (B) — 8 loads each
  bf16x8 kA0 = *(const bf16x8*)(Kp + koff);
  bf16x8 kA1 = *(const bf16x8*)(Kp + koff + 16);
  uint2 bA0 = *(const uint2*)(biasM + boff);
  uint2 bA1 = *(const uint2*)(biasM + boff + 8);
  uint2 bA2 = *(const uint2*)(biasM + boff + 16);
  uint2 bA3 = *(const uint2*)(biasM + boff + 24);
  bf16x8 vA0 = *(const bf16x8*)(Vt + voff);
  bf16x8 vA1 = *(const bf16x8*)(Vt + voff + 16);
  bf16x8 kB0 = *(const bf16x8*)(Kp + koff + 1024);
  bf16x8 kB1 = *(const bf16x8*)(Kp + koff + 1040);
  uint2 bB0 = *(const uint2*)(biasM + boff + 32);
  uint2 bB1 = *(const uint2*)(biasM + boff + 40);
  uint2 bB2 = *(const uint2*)(biasM + boff + 48);
  uint2 bB3 = *(const uint2*)(biasM + boff + 56);
  bf16x8 vB0 = *(const bf16x8*)(Vt + voff + 32);
  bf16x8 vB1 = *(const bf16x8*)(Vt + voff + 48);

  f32x16 O;
  #pragma unroll
  for (int i = 0; i < 16; ++i) O[i] = 0.f;
  f32x4 racc = {0.f, 0.f, 0.f, 0.f};

  union U8 { uint32_t u[4]; bf16x8 v; };

  auto tile = [&](bf16x8& K0, bf16x8& K1, bf16x8& V0, bf16x8& V1,
                  uint2& B0, uint2& B1, uint2& B2, uint2& B3,
                  uint32_t kpre, uint32_t vpre, uint32_t bpre) {
    // this tile's 8 loads (issued one tile ago) done; other buffer's 8 stay in flight
    asm volatile("s_waitcnt vmcnt(8)" ::: "memory");
    // C-init = bias (S[r] for kv=(r&3)+8*(r>>2)+4*hi5, q=lq)
    f32x16 S;
    S[0]  = __uint_as_float(B0.x << 16);
    S[1]  = __uint_as_float(B0.x & 0xFFFF0000u);
    S[2]  = __uint_as_float(B0.y << 16);
    S[3]  = __uint_as_float(B0.y & 0xFFFF0000u);
    S[4]  = __uint_as_float(B1.x << 16);
    S[5]  = __uint_as_float(B1.x & 0xFFFF0000u);
    S[6]  = __uint_as_float(B1.y << 16);
    S[7]  = __uint_as_float(B1.y & 0xFFFF0000u);
    S[8]  = __uint_as_float(B2.x << 16);
    S[9]  = __uint_as_float(B2.x & 0xFFFF0000u);
    S[10] = __uint_as_float(B2.y << 16);
    S[11] = __uint_as_float(B2.y & 0xFFFF0000u);
    S[12] = __uint_as_float(B3.x << 16);
    S[13] = __uint_as_float(B3.x & 0xFFFF0000u);
    S[14] = __uint_as_float(B3.y << 16);
    S[15] = __uint_as_float(B3.y & 0xFFFF0000u);
    // S^T[kv][q] = bias + K · (Qh + Ql)
    S = mfma32(K0, qh0, S);
    S = mfma32(K1, qh1, S);
    S = mfma32(K0, ql0, S);
    S = mfma32(K1, ql1, S);
    // K/bias consumed -> refill for tile t+2 (pinned here)
    K0 = *(const bf16x8*)(Kp + koff + kpre);
    K1 = *(const bf16x8*)(Kp + koff + kpre + 16);
    B0 = *(const uint2*)(biasM + boff + bpre);
    B1 = *(const uint2*)(biasM + boff + bpre + 8);
    B2 = *(const uint2*)(biasM + boff + bpre + 16);
    B3 = *(const uint2*)(biasM + boff + bpre + 24);
    __builtin_amdgcn_sched_barrier(0);
    // exp2 + rowsum accum
    float e0  = exp2_hw(S[0]),  e1  = exp2_hw(S[1]),  e2  = exp2_hw(S[2]),  e3  = exp2_hw(S[3]);
    float e4  = exp2_hw(S[4]),  e5  = exp2_hw(S[5]),  e6  = exp2_hw(S[6]),  e7  = exp2_hw(S[7]);
    float e8  = exp2_hw(S[8]),  e9  = exp2_hw(S[9]),  e10 = exp2_hw(S[10]), e11 = exp2_hw(S[11]);
    float e12 = exp2_hw(S[12]), e13 = exp2_hw(S[13]), e14 = exp2_hw(S[14]), e15 = exp2_hw(S[15]);
    racc[0] += e0 + e4;  racc[1] += e1 + e5;
    racc[2] += e2 + e6;  racc[3] += e3 + e7;
    racc[0] += e8 + e12; racc[1] += e9 + e13;
    racc[2] += e10 + e14; racc[3] += e11 + e15;
    // pack P -> bf16, lane-half exchange -> A-fragments
    uint32_t u0 = cvtpk_bf16(e0,  e1);
    uint32_t u1 = cvtpk_bf16(e2,  e3);
    uint32_t u2 = cvtpk_bf16(e4,  e5);
    uint32_t u3 = cvtpk_bf16(e6,  e7);
    uint32_t u4 = cvtpk_bf16(e8,  e9);
    uint32_t u5 = cvtpk_bf16(e10, e11);
    uint32_t u6 = cvtpk_bf16(e12, e13);
    uint32_t u7 = cvtpk_bf16(e14, e15);
    pl32swap(u0, u2);
    pl32swap(u1, u3);
    pl32swap(u4, u6);
    pl32swap(u5, u7);
    U8 a1; a1.u[0] = u0; a1.u[1] = u1; a1.u[2] = u2; a1.u[3] = u3;
    U8 a2; a2.u[0] = u4; a2.u[1] = u5; a2.u[2] = u6; a2.u[3] = u7;
    // O[q][d] += P @ V
    O = mfma32(a1.v, V0, O);
    O = mfma32(a2.v, V1, O);
    // V consumed -> refill for tile t+2 (pinned)
    V0 = *(const bf16x8*)(Vt + voff + vpre);
    V1 = *(const bf16x8*)(Vt + voff + vpre + 16);
    __builtin_amdgcn_sched_barrier(0);
  };

  #pragma unroll 1
  for (int it = 0; it < 16; ++it) {
    tile(kA0, kA1, vA0, vA1, bA0, bA1, bA2, bA3, 2048u, 64u, 64u);
    tile(kB0, kB1, vB0, vB1, bB0, bB1, bB2, bB3, 3072u, 96u, 96u);
    koff += 2048u; voff += 64u; boff += 64u;
  }

  // rsum: lane holds 16-slot partial for q=lq; partner half has the rest
  float rsum = (racc[0] + racc[1]) + (racc[2] + racc[3]);
  rsum += __shfl_xor(rsum, 32);

  #pragma unroll
  for (int r = 0; r < 16; ++r) {
    int qrow = (r & 3) + 8 * (r >> 2) + 4 * hi5;
    float tot = __shfl(rsum, qrow);
    float o = O[r] / tot;
    size_t ro = (size_t)(m0w + qrow) * 512 + h * 32 + lq;
    bf16 h0 = (bf16)o;
    Oh[ro] = h0;
    Ol[ro] = (bf16)(o - (float)h0);
  }
}

// ---------------- launch ----------------
extern "C" void kernel_launch(void* const* d_in, const int* in_sizes, int n_in,
                              void* d_out, int out_size, void* d_ws, size_t ws_size,
                              hipStream_t stream) {
  const float* x     = (const float*)d_in[0];
  const float* wqkv  = (const float*)d_in[1];
  const float* bqkv  = (const float*)d_in[2];
  const float* wproj = (const float*)d_in[3];
  const float* bproj = (const float*)d_in[4];
  const float* btab  = (const float*)d_in[5];
  // d_in[6] rel_index: unused (index computed analytically)
  float* out = (float*)d_out;

  char* ws = (char*)d_ws;
  size_t off = 0;
  auto walloc = [&](size_t bytes) {
    void* p = ws + off;
    off += (bytes + 255) & ~(size_t)255;
    return p;
  };
  bf16* Xh      = (bf16*)walloc((size_t)16384 * 512 * 2);
  bf16* Xl      = (bf16*)walloc((size_t)16384 * 512 * 2);
  bf16* wqkvTh  = (bf16*)walloc((size_t)1536 * 512 * 2);
  bf16* wqkvTl  = (bf16*)walloc((size_t)1536 * 512 * 2);
  bf16* wprojTh = (bf16*)walloc((size_t)512 * 512 * 2);
  bf16* wprojTl = (bf16*)walloc((size_t)512 * 512 * 2);
  bf16* Qh      = (bf16*)walloc((size_t)16384 * 512 * 2);
  bf16* Ql      = (bf16*)walloc((size_t)16384 * 512 * 2);
  bf16* Kp      = (bf16*)walloc((size_t)16384 * 512 * 2 + 65536);
  bf16* Vt      = (bf16*)walloc((size_t)16384 * 512 * 2 + 65536);
  bf16* biasM   = (bf16*)walloc((size_t)16 * 1024 * 1024 * 2 + 65536);
  bf16* Oh      = (bf16*)walloc((size_t)16384 * 512 * 2);
  bf16* Ol      = (bf16*)walloc((size_t)16384 * 512 * 2);

  const int prep_total = 16384 * 512 / 4 + 1536 * 512 + 512 * 512;
  prep_kernel<<<(prep_total + 255) / 256, 256, 0, stream>>>(
      x, wqkv, wproj, Xh, Xl, wqkvTh, wqkvTl, wprojTh, wprojTl);

  bias_kernel<<<16 * 1024 * 128 / 256, 256, 0, stream>>>(btab, biasM);

  gemm_kernel<0><<<12 * 128, 256, 0, stream>>>(
      Xh, Xl, wqkvTh, wqkvTl, bqkv, Qh, Ql, Kp, Vt, nullptr);

  attn_kernel<<<2048, 256, 0, stream>>>(Qh, Ql, Kp, Vt, biasM, Oh, Ol);

  gemm_kernel<1><<<4 * 128, 256, 0, stream>>>(
      Oh, Ol, wprojTh, wprojTl, bproj,
      nullptr, nullptr, nullptr, nullptr, out);
}

// Round 7
// 272.859 us; speedup vs baseline: 1.8212x; 1.5375x over previous
//
#include <hip/hip_runtime.h>
#include <hip/hip_bf16.h>
#include <cstdint>
#include <cstddef>

typedef __bf16 bf16;
typedef __attribute__((ext_vector_type(8))) __bf16 bf16x8;
typedef __attribute__((ext_vector_type(4))) __bf16 bf16x4v;
typedef __attribute__((ext_vector_type(4))) float f32x4;
typedef __attribute__((ext_vector_type(16))) float f32x16;

#define LOG2E 1.4426950408889634f
#define QK_SCALE 0.17677669529663687f

__device__ __forceinline__ f32x4 mfma16(bf16x8 a, bf16x8 b, f32x4 c) {
  return __builtin_amdgcn_mfma_f32_16x16x32_bf16(a, b, c, 0, 0, 0);
}
__device__ __forceinline__ f32x16 mfma32(bf16x8 a, bf16x8 b, f32x16 c) {
  return __builtin_amdgcn_mfma_f32_32x32x16_bf16(a, b, c, 0, 0, 0);
}
__device__ __forceinline__ float exp2_hw(float x) {
  float r; asm("v_exp_f32 %0, %1" : "=v"(r) : "v"(x)); return r;
}
__device__ __forceinline__ uint32_t cvtpk_bf16(float a, float b) {
  uint32_t r; asm("v_cvt_pk_bf16_f32 %0, %1, %2" : "=v"(r) : "v"(a), "v"(b)); return r;
}
__device__ __forceinline__ void pl32swap(uint32_t& a, uint32_t& b) {
  asm("v_permlane32_swap_b32 %0, %1" : "+v"(a), "+v"(b));
}
__device__ __forceinline__ float lo16f(uint32_t u) { return __uint_as_float(u << 16); }
__device__ __forceinline__ float hi16f(uint32_t u) { return __uint_as_float(u & 0xFFFF0000u); }

// ---------------- prep: split x, transpose+split weights ----------------
__global__ __launch_bounds__(256) void prep_kernel(
    const float* __restrict__ x, const float* __restrict__ wqkv, const float* __restrict__ wproj,
    bf16* __restrict__ Xh, bf16* __restrict__ Xl,
    bf16* __restrict__ wqkvTh, bf16* __restrict__ wqkvTl,
    bf16* __restrict__ wprojTh, bf16* __restrict__ wprojTl)
{
  const int X4 = 16384 * 512 / 4;
  int e = blockIdx.x * 256 + threadIdx.x;
  if (e < X4) {
    f32x4 v = *(const f32x4*)(x + (size_t)e * 4);
    bf16x4v hi, lo;
    #pragma unroll
    for (int j = 0; j < 4; ++j) {
      bf16 h = (bf16)v[j];
      hi[j] = h;
      lo[j] = (bf16)(v[j] - (float)h);
    }
    *(bf16x4v*)(Xh + (size_t)e * 4) = hi;
    *(bf16x4v*)(Xl + (size_t)e * 4) = lo;
  } else if (e < X4 + 1536 * 512) {
    int e2 = e - X4;
    int n = e2 >> 9, k = e2 & 511;
    float v = wqkv[k * 1536 + n];
    bf16 h = (bf16)v;
    wqkvTh[e2] = h;
    wqkvTl[e2] = (bf16)(v - (float)h);
  } else {
    int e3 = e - (X4 + 1536 * 512);
    if (e3 < 512 * 512) {
      int n = e3 >> 9, k = e3 & 511;
      float v = wproj[k * 512 + n];
      bf16 h = (bf16)v;
      wprojTh[e3] = h;
      wprojTl[e3] = (bf16)(v - (float)h);
    }
  }
}

// ---------------- bias: lane-packed tiles biasM[h][qb][kvb][lane][16] ----------------
// reg r of lane (lq,hi5) holds bias(q = qb*32+lq, kv = kvb*32 + (r&3)+8*(r>>2)+4*hi5) * log2e
__global__ __launch_bounds__(256) void bias_kernel(
    const float* __restrict__ btab, bf16* __restrict__ biasM)
{
  int t = blockIdx.x * 256 + threadIdx.x;     // 1M threads: [h][qb][kvb][lane]
  int lane = t & 63;
  int kvb  = (t >> 6) & 31;
  int qb   = (t >> 11) & 31;
  int h    = t >> 16;
  int lq = lane & 31, hi5 = lane >> 5;
  int q = qb * 32 + lq;
  int base_q = ((q >> 5) + 31) * 63 + (q & 31) + 31;
  bf16 out[16];
  #pragma unroll
  for (int r = 0; r < 16; ++r) {
    int kv = kvb * 32 + (r & 3) + 8 * (r >> 2) + 4 * hi5;
    int idx = base_q - ((kv >> 5) * 63 + (kv & 31));
    out[r] = (bf16)(btab[idx * 16 + h] * LOG2E);
  }
  *(bf16x8*)(biasM + (size_t)t * 16) = *(bf16x8*)&out[0];
  *(bf16x8*)(biasM + (size_t)t * 16 + 8) = *(bf16x8*)&out[8];
}

// ---------------- split-bf16 GEMM: C[M,N] = (Ah+Al) @ (Bh+Bl) + bias ----------------
// MODE 0: N=1536 -> Q(scaled,split) [m][512]; K [bh][2][1024][16]; V [bh][128][32][8]
// MODE 1: N=512  -> fp32 out
template<int MODE>
__global__ __launch_bounds__(256) void gemm_kernel(
    const bf16* __restrict__ Ah, const bf16* __restrict__ Al,
    const bf16* __restrict__ BTh, const bf16* __restrict__ BTl,
    const float* __restrict__ bvec,
    bf16* __restrict__ Qh, bf16* __restrict__ Ql,
    bf16* __restrict__ Kp, bf16* __restrict__ Vt,
    float* __restrict__ out)
{
  constexpr int NT = (MODE == 0) ? 12 : 4;
  __shared__ bf16 Ash[128][40];
  __shared__ bf16 Asl[128][40];
  __shared__ bf16 Bsh[128][40];
  __shared__ bf16 Bsl[128][40];

  const int bx = blockIdx.x % NT;
  const int by = blockIdx.x / NT;
  const int row0 = by * 128, col0 = bx * 128;
  const int tid = threadIdx.x;
  const int lane = tid & 63, wave = tid >> 6;
  const int l15 = lane & 15, l4 = lane >> 4;
  const int wr = wave >> 1, wc = wave & 1;

  f32x4 acc[4][4];
  #pragma unroll
  for (int i = 0; i < 4; ++i)
    #pragma unroll
    for (int j = 0; j < 4; ++j) acc[i][j] = (f32x4){0.f, 0.f, 0.f, 0.f};

  for (int kt = 0; kt < 16; ++kt) {
    #pragma unroll
    for (int p = 0; p < 2; ++p) {
      int s = tid + p * 256;
      int r = s >> 2, c = (s & 3) * 8;
      size_t ao = (size_t)(row0 + r) * 512 + kt * 32 + c;
      size_t bo = (size_t)(col0 + r) * 512 + kt * 32 + c;
      *(bf16x8*)&Ash[r][c] = *(const bf16x8*)(Ah + ao);
      *(bf16x8*)&Asl[r][c] = *(const bf16x8*)(Al + ao);
      *(bf16x8*)&Bsh[r][c] = *(const bf16x8*)(BTh + bo);
      *(bf16x8*)&Bsl[r][c] = *(const bf16x8*)(BTl + bo);
    }
    __syncthreads();

    bf16x8 ah[4], al[4], bh[4], bl[4];
    #pragma unroll
    for (int mf = 0; mf < 4; ++mf) {
      int r = wr * 64 + mf * 16 + l15;
      ah[mf] = *(const bf16x8*)&Ash[r][l4 * 8];
      al[mf] = *(const bf16x8*)&Asl[r][l4 * 8];
    }
    #pragma unroll
    for (int nf = 0; nf < 4; ++nf) {
      int c = wc * 64 + nf * 16 + l15;
      bh[nf] = *(const bf16x8*)&Bsh[c][l4 * 8];
      bl[nf] = *(const bf16x8*)&Bsl[c][l4 * 8];
    }
    #pragma unroll
    for (int mf = 0; mf < 4; ++mf)
      #pragma unroll
      for (int nf = 0; nf < 4; ++nf) {
        f32x4 a = acc[mf][nf];
        a = mfma16(ah[mf], bh[nf], a);
        a = mfma16(ah[mf], bl[nf], a);
        a = mfma16(al[mf], bh[nf], a);
        acc[mf][nf] = a;
      }
    __syncthreads();
  }

  #pragma unroll
  for (int mf = 0; mf < 4; ++mf) {
    #pragma unroll
    for (int nf = 0; nf < 4; ++nf) {
      int colb = col0 + wc * 64 + nf * 16 + l15;
      float bb = bvec[colb];
      #pragma unroll
      for (int i = 0; i < 4; ++i) {
        int m = row0 + wr * 64 + mf * 16 + l4 * 4 + i;
        float v = acc[mf][nf][i] + bb;
        if (MODE == 1) {
          out[(size_t)m * 512 + colb] = v;
        } else {
          int t = colb >> 9, cc = colb & 511;
          int b = m >> 10, n = m & 1023;
          int hh = cc >> 5, d = cc & 31;
          int bh2 = b * 16 + hh;
          if (t == 0) {
            v *= (QK_SCALE * LOG2E);
            bf16 h = (bf16)v;
            Qh[(size_t)m * 512 + cc] = h;
            Ql[(size_t)m * 512 + cc] = (bf16)(v - (float)h);
          } else if (t == 1) {
            Kp[((size_t)(bh2 * 2 + (d >> 4)) * 1024 + n) * 16 + (d & 15)] = (bf16)v;
          } else {
            Vt[((size_t)(bh2 * 128 + (n >> 3)) * 32 + d) * 8 + (n & 7)] = (bf16)v;
          }
        }
      }
    }
  }
}

// ---------------- fused flash attention: dense fragment-order loads, bias C-init ----------------
// grid 2048. Swizzle: xcd = bid&7 owns heads {2*xcd, 2*xcd+1}; within an h,
// the 16 batch-blocks of one qt run adjacent -> bias slice L2-reused.
__global__ __launch_bounds__(256, 4) void attn_kernel(
    const bf16* __restrict__ Qh, const bf16* __restrict__ Ql,
    const bf16* __restrict__ Kp, const bf16* __restrict__ Vt,
    const bf16* __restrict__ biasM,
    bf16* __restrict__ Oh, bf16* __restrict__ Ol)
{
  const int bid = blockIdx.x;
  const int xcd = bid & 7, slot = bid >> 3;
  const int h = xcd * 2 + (slot >> 7);
  const int rest = slot & 127;
  const int qt = rest >> 4, b = rest & 15;
  const int bh = b * 16 + h;
  const int tid = threadIdx.x, lane = tid & 63, wave = tid >> 6;
  const int lq = lane & 31, hi5 = lane >> 5;

  const int qloc = qt * 128 + wave * 32;
  const int qb = qt * 4 + wave;            // q-tile-of-32 index
  const int m0w = b * 1024 + qloc;

  // Q B-fragments (col=q=lq, k=d=8*hi5+j), two d-halves, hi+lo split
  const uint32_t qoff = (uint32_t)(m0w + lq) * 512u + (uint32_t)h * 32u + (uint32_t)hi5 * 8u;
  const bf16x8 qh0 = *(const bf16x8*)(Qh + qoff);
  const bf16x8 qh1 = *(const bf16x8*)(Qh + qoff + 16);
  const bf16x8 ql0 = *(const bf16x8*)(Ql + qoff);
  const bf16x8 ql1 = *(const bf16x8*)(Ql + qoff + 16);

  // dense per-wave element offsets (all loads: contiguous 1KB per instruction)
  uint32_t koff = (uint32_t)bh * 32768u + (uint32_t)lq * 16u + (uint32_t)hi5 * 8u;   // K [bh][2][1024][16]
  uint32_t voff = (uint32_t)bh * 32768u + (uint32_t)hi5 * 256u + (uint32_t)lq * 8u;  // V [bh][128][32][8]
  uint32_t boff = ((uint32_t)h * 32u + (uint32_t)qb) * 32768u + (uint32_t)lane * 16u; // bias lane-packed

  // prologue: tile 0 (A bufs, 6 loads) then tile 1 (B bufs, 6 loads)
  bf16x8 kA0 = *(const bf16x8*)(Kp + koff);
  bf16x8 kA1 = *(const bf16x8*)(Kp + koff + 16384);
  uint4  baA = *(const uint4*)(biasM + boff);
  uint4  bbA = *(const uint4*)(biasM + boff + 8);
  bf16x8 vA0 = *(const bf16x8*)(Vt + voff);
  bf16x8 vA1 = *(const bf16x8*)(Vt + voff + 512);
  bf16x8 kB0 = *(const bf16x8*)(Kp + koff + 512);
  bf16x8 kB1 = *(const bf16x8*)(Kp + koff + 16384 + 512);
  uint4  baB = *(const uint4*)(biasM + boff + 1024);
  uint4  bbB = *(const uint4*)(biasM + boff + 1024 + 8);
  bf16x8 vB0 = *(const bf16x8*)(Vt + voff + 1024);
  bf16x8 vB1 = *(const bf16x8*)(Vt + voff + 1024 + 512);

  f32x16 O;
  #pragma unroll
  for (int i = 0; i < 16; ++i) O[i] = 0.f;
  f32x4 racc = {0.f, 0.f, 0.f, 0.f};

  union U8 { uint32_t u[4]; bf16x8 v; };

  auto tile = [&](bf16x8& K0, bf16x8& K1, bf16x8& V0, bf16x8& V1,
                  uint4& Ba, uint4& Bb,
                  uint32_t Tk, uint32_t Tv, uint32_t Tb,
                  uint32_t kpre, uint32_t vpre, uint32_t bpre) {
    // this tile's 6 loads done; other buffer's 6 stay in flight
    asm volatile("s_waitcnt vmcnt(6)" ::: "memory");
    // C-init = bias (reg r: kv=(r&3)+8*(r>>2)+4*hi5, q=lq)
    f32x16 S;
    S[0]  = lo16f(Ba.x); S[1]  = hi16f(Ba.x);
    S[2]  = lo16f(Ba.y); S[3]  = hi16f(Ba.y);
    S[4]  = lo16f(Ba.z); S[5]  = hi16f(Ba.z);
    S[6]  = lo16f(Ba.w); S[7]  = hi16f(Ba.w);
    S[8]  = lo16f(Bb.x); S[9]  = hi16f(Bb.x);
    S[10] = lo16f(Bb.y); S[11] = hi16f(Bb.y);
    S[12] = lo16f(Bb.z); S[13] = hi16f(Bb.z);
    S[14] = lo16f(Bb.w); S[15] = hi16f(Bb.w);
    // S^T[kv][q] = bias + K · (Qh + Ql)
    S = mfma32(K0, qh0, S);
    S = mfma32(K1, qh1, S);
    S = mfma32(K0, ql0, S);
    S = mfma32(K1, ql1, S);
    // K/bias consumed -> refill for tile t+2
    K0 = *(const bf16x8*)(Kp + koff + kpre);
    K1 = *(const bf16x8*)(Kp + koff + 16384 + kpre);
    Ba = *(const uint4*)(biasM + boff + bpre);
    Bb = *(const uint4*)(biasM + boff + bpre + 8);
    __builtin_amdgcn_sched_barrier(0);
    // exp2 + rowsum
    float e0  = exp2_hw(S[0]),  e1  = exp2_hw(S[1]),  e2  = exp2_hw(S[2]),  e3  = exp2_hw(S[3]);
    float e4  = exp2_hw(S[4]),  e5  = exp2_hw(S[5]),  e6  = exp2_hw(S[6]),  e7  = exp2_hw(S[7]);
    float e8  = exp2_hw(S[8]),  e9  = exp2_hw(S[9]),  e10 = exp2_hw(S[10]), e11 = exp2_hw(S[11]);
    float e12 = exp2_hw(S[12]), e13 = exp2_hw(S[13]), e14 = exp2_hw(S[14]), e15 = exp2_hw(S[15]);
    racc[0] += e0 + e4;   racc[1] += e1 + e5;
    racc[2] += e2 + e6;   racc[3] += e3 + e7;
    racc[0] += e8 + e12;  racc[1] += e9 + e13;
    racc[2] += e10 + e14; racc[3] += e11 + e15;
    // pack P -> bf16, lane-half exchange -> A-fragments
    uint32_t u0 = cvtpk_bf16(e0,  e1);
    uint32_t u1 = cvtpk_bf16(e2,  e3);
    uint32_t u2 = cvtpk_bf16(e4,  e5);
    uint32_t u3 = cvtpk_bf16(e6,  e7);
    uint32_t u4 = cvtpk_bf16(e8,  e9);
    uint32_t u5 = cvtpk_bf16(e10, e11);
    uint32_t u6 = cvtpk_bf16(e12, e13);
    uint32_t u7 = cvtpk_bf16(e14, e15);
    pl32swap(u0, u2);
    pl32swap(u1, u3);
    pl32swap(u4, u6);
    pl32swap(u5, u7);
    U8 a1; a1.u[0] = u0; a1.u[1] = u1; a1.u[2] = u2; a1.u[3] = u3;
    U8 a2; a2.u[0] = u4; a2.u[1] = u5; a2.u[2] = u6; a2.u[3] = u7;
    // O[q][d] += P @ V
    O = mfma32(a1.v, V0, O);
    O = mfma32(a2.v, V1, O);
    // V consumed -> refill for tile t+2
    V0 = *(const bf16x8*)(Vt + voff + vpre);
    V1 = *(const bf16x8*)(Vt + voff + vpre + 512);
    __builtin_amdgcn_sched_barrier(0);
  };

  #pragma unroll 1
  for (int it = 0; it < 16; ++it) {
    tile(kA0, kA1, vA0, vA1, baA, bbA, 0u, 0u, 0u, 1024u, 2048u, 2048u);
    tile(kB0, kB1, vB0, vB1, baB, bbB, 512u, 1024u, 1024u, 1536u, 3072u, 3072u);
    koff += 1024u; voff += 2048u; boff += 2048u;
  }

  // rsum: lane holds 16-slot partial for q=lq; partner half has the rest
  float rsum = (racc[0] + racc[1]) + (racc[2] + racc[3]);
  rsum += __shfl_xor(rsum, 32);

  #pragma unroll
  for (int r = 0; r < 16; ++r) {
    int qrow = (r & 3) + 8 * (r >> 2) + 4 * hi5;
    float tot = __shfl(rsum, qrow);
    float o = O[r] / tot;
    size_t ro = (size_t)(m0w + qrow) * 512 + h * 32 + lq;
    bf16 h0 = (bf16)o;
    Oh[ro] = h0;
    Ol[ro] = (bf16)(o - (float)h0);
  }
}

// ---------------- launch ----------------
extern "C" void kernel_launch(void* const* d_in, const int* in_sizes, int n_in,
                              void* d_out, int out_size, void* d_ws, size_t ws_size,
                              hipStream_t stream) {
  const float* x     = (const float*)d_in[0];
  const float* wqkv  = (const float*)d_in[1];
  const float* bqkv  = (const float*)d_in[2];
  const float* wproj = (const float*)d_in[3];
  const float* bproj = (const float*)d_in[4];
  const float* btab  = (const float*)d_in[5];
  // d_in[6] rel_index: unused (index computed analytically)
  float* out = (float*)d_out;

  char* ws = (char*)d_ws;
  size_t off = 0;
  auto walloc = [&](size_t bytes) {
    void* p = ws + off;
    off += (bytes + 255) & ~(size_t)255;
    return p;
  };
  bf16* Xh      = (bf16*)walloc((size_t)16384 * 512 * 2);
  bf16* Xl      = (bf16*)walloc((size_t)16384 * 512 * 2);
  bf16* wqkvTh  = (bf16*)walloc((size_t)1536 * 512 * 2);
  bf16* wqkvTl  = (bf16*)walloc((size_t)1536 * 512 * 2);
  bf16* wprojTh = (bf16*)walloc((size_t)512 * 512 * 2);
  bf16* wprojTl = (bf16*)walloc((size_t)512 * 512 * 2);
  bf16* Qh      = (bf16*)walloc((size_t)16384 * 512 * 2);
  bf16* Ql      = (bf16*)walloc((size_t)16384 * 512 * 2);
  bf16* Kp      = (bf16*)walloc((size_t)16384 * 512 * 2 + 65536);
  bf16* Vt      = (bf16*)walloc((size_t)16384 * 512 * 2 + 65536);
  bf16* biasM   = (bf16*)walloc((size_t)16 * 1024 * 1024 * 2 + 65536);
  bf16* Oh      = (bf16*)walloc((size_t)16384 * 512 * 2);
  bf16* Ol      = (bf16*)walloc((size_t)16384 * 512 * 2);

  const int prep_total = 16384 * 512 / 4 + 1536 * 512 + 512 * 512;
  prep_kernel<<<(prep_total + 255) / 256, 256, 0, stream>>>(
      x, wqkv, wproj, Xh, Xl, wqkvTh, wqkvTl, wprojTh, wprojTl);

  bias_kernel<<<4096, 256, 0, stream>>>(btab, biasM);

  gemm_kernel<0><<<12 * 128, 256, 0, stream>>>(
      Xh, Xl, wqkvTh, wqkvTl, bqkv, Qh, Ql, Kp, Vt, nullptr);

  attn_kernel<<<2048, 256, 0, stream>>>(Qh, Ql, Kp, Vt, biasM, Oh, Ol);

  gemm_kernel<1><<<4 * 128, 256, 0, stream>>>(
      Oh, Ol, wprojTh, wprojTl, bproj,
      nullptr, nullptr, nullptr, nullptr, out);
}